// Round 6
// baseline (44.409 us; speedup 1.0000x reference)
//
#include <hip/hip_runtime.h>

// Problem: N=64 graphs, K=64 nodes, C_IN=128, C=128, fp32.
// Pipeline (3 launches), all GEMM weights staged in LDS (broadcast reads):
//   K1: h = x @ W_lin[:, :128].T + b_lin + t*W_lin[:,128]
//   K2f: binary blocks: A=h@Wb1L.T, Bb=h@Wb1R.T+bb1 (LDS only);
//          U=exp2(k*A), V=exp2(k*Bb); S'=(63-2*sum_{i!=j} rcp(U_j*V_i+1))/64
//        unary blocks: T = tanh(h@Wu1.T + bu1)
//   K4: out = T@Wu2.T + S'@Wb2.T + bu2 + (63/64)*bb2
#define LS 132  // LDS row stride (dwords): (4l)%32 -> 8 dwords/bank (min) for b128
#define USTR 20 // U/V row stride: (20l)%32 -> 8 dwords/bank (min)
#define ROW_ELEMS 524288  // 4096*128
#define EXPC 2.8853900817779268f  // 2*log2(e)

__device__ __forceinline__ float sigterm(float x) {
    float e = __builtin_amdgcn_exp2f(x * EXPC);
    return __builtin_amdgcn_rcpf(e + 1.0f);
}
__device__ __forceinline__ float tanh_fast(float x) {
    return 1.0f - 2.0f * sigterm(x);
}

// Stage 64 rows x 128 cols of X (row stride 128) into xs[64][LS].
__device__ __forceinline__ void stage64(const float* __restrict__ X, int r0,
                                        float* __restrict__ xs, int tid) {
    const float4* src = reinterpret_cast<const float4*>(X + (size_t)r0 * 128);
#pragma unroll
    for (int p = 0; p < 8; ++p) {
        const int q = p * 256 + tid;  // 2048 float4s
        const int r = q >> 5;
        const int k4 = (q & 31) << 2;
        *reinterpret_cast<float4*>(&xs[r * LS + k4]) = src[q];
    }
}

// Stage NR weight rows (row stride RS, 128 cols used) into wt[NR][128].
template <int NR, int RS>
__device__ __forceinline__ void stage_w(const float* __restrict__ W, int row0,
                                        float* __restrict__ wt, int tid) {
    if constexpr (RS == 128) {
#pragma unroll
        for (int p = 0; p < NR / 8; ++p) {
            const int q = p * 256 + tid;  // NR*32 float4s
            const int row = q >> 5;
            const int k4 = (q & 31) << 2;
            *reinterpret_cast<float4*>(&wt[row * 128 + k4]) =
                *reinterpret_cast<const float4*>(W + (row0 + row) * RS + k4);
        }
    } else {  // unaligned row stride: scalar-coalesced (256B per wave per row-half)
#pragma unroll
        for (int p = 0; p < NR / 2; ++p) {
            const int q = p * 256 + tid;  // NR*128 floats
            const int row = q >> 7;
            const int col = q & 127;
            wt[row * 128 + col] = W[(row0 + row) * RS + col];
        }
    }
}

// 128-k inner product vs NC LDS-staged weight cols (wave-uniform broadcast
// reads); lane's activation row via per-lane b128 (bank-balanced).
template <int NC>
__device__ __forceinline__ void accum_lds(const float* __restrict__ xs,
                                          const float* __restrict__ wt,
                                          int lane, int wc0,
                                          float (&acc)[NC]) {
#pragma unroll 8
    for (int kq = 0; kq < 32; ++kq) {
        const float4 a =
            *reinterpret_cast<const float4*>(&xs[lane * LS + kq * 4]);
#pragma unroll
        for (int c = 0; c < NC; ++c) {
            const float4 w = *reinterpret_cast<const float4*>(
                &wt[(wc0 + c) * 128 + kq * 4]);
            acc[c] = fmaf(a.x, w.x, acc[c]);
            acc[c] = fmaf(a.y, w.y, acc[c]);
            acc[c] = fmaf(a.z, w.z, acc[c]);
            acc[c] = fmaf(a.w, w.w, acc[c]);
        }
    }
}

// K1: h = x@W_lin[:,:128].T + b_lin + t*W_lin[:,128].
// grid (8,64): 16 cols/block, 4/wave. LDS 42 KB -> 3 blocks/CU.
__global__ __launch_bounds__(256) void k1_h(const float* __restrict__ x,
                                            const float* __restrict__ W_lin,
                                            const float* __restrict__ b_lin,
                                            const float* __restrict__ tp,
                                            float* __restrict__ h) {
    __shared__ float xs[64 * LS];
    __shared__ float wt[16 * 128];
    const int tid = threadIdx.x;
    const int lane = tid & 63;
    const int wv = __builtin_amdgcn_readfirstlane(tid >> 6);
    const int r0 = blockIdx.y * 64;
    const int cb = blockIdx.x * 16;
    const int cg = cb + wv * 4;
    stage64(x, r0, xs, tid);
    stage_w<16, 129>(W_lin, cb, wt, tid);
    __syncthreads();
    float acc[4] = {0.f, 0.f, 0.f, 0.f};
    accum_lds<4>(xs, wt, lane, wv * 4, acc);
    const float tv = tp[0];
    float4 o;
    o.x = acc[0] + b_lin[cg + 0] + tv * W_lin[(cg + 0) * 129 + 128];
    o.y = acc[1] + b_lin[cg + 1] + tv * W_lin[(cg + 1) * 129 + 128];
    o.z = acc[2] + b_lin[cg + 2] + tv * W_lin[(cg + 2) * 129 + 128];
    o.w = acc[3] + b_lin[cg + 3] + tv * W_lin[(cg + 3) * 129 + 128];
    *reinterpret_cast<float4*>(&h[(size_t)(r0 + lane) * 128 + cg]) = o;
}

// K2f: bx < 8  -> binary chunk of 16 channels for graph blockIdx.y
//      bx >= 8 -> unary T cols (32/block, 8/wave)
// LDS: xs[64*LS] + wt[32*128] = 50.2 KB -> 3 blocks/CU. us/vs alias xs.
__global__ __launch_bounds__(256) void k2_fused(
    const float* __restrict__ h, const float* __restrict__ Wu1,
    const float* __restrict__ bu1, const float* __restrict__ Wb1,
    const float* __restrict__ bb1, float* __restrict__ T,
    float* __restrict__ S) {
    __shared__ float smem[64 * LS + 32 * 128];
    float* xs = smem;
    float* wt = smem + 64 * LS;
    float* us = smem;               // alias: xs region (dead after GEMM)
    float* vs = smem + 64 * USTR;
    const int tid = threadIdx.x;
    const int lane = tid & 63;
    const int wv = __builtin_amdgcn_readfirstlane(tid >> 6);
    const int r0 = blockIdx.y * 64;  // graph n * 64
    const int bx = blockIdx.x;
    stage64(h, r0, xs, tid);
    {   // Stage 32 weight rows (binary: 16 A-rows + 16 B-rows; unary: 32 Wu1)
        const int cb = bx < 8 ? bx * 16 : 0;
        const int cg0 = bx >= 8 ? (bx - 8) * 32 : 0;
#pragma unroll
        for (int p = 0; p < 4; ++p) {
            const int q = p * 256 + tid;  // 1024 float4s
            const int row = q >> 5;
            const int k4 = (q & 31) << 2;
            const float* src;
            if (bx < 8)
                src = (row < 16) ? (Wb1 + (cb + row) * 256 + k4)
                                 : (Wb1 + (cb + row - 16) * 256 + 128 + k4);
            else
                src = Wu1 + (cg0 + row) * 128 + k4;
            *reinterpret_cast<float4*>(&wt[row * 128 + k4]) =
                *reinterpret_cast<const float4*>(src);
        }
    }
    __syncthreads();

    if (bx < 8) {  // ---- binary chunk (long pole; dispatched first) ----
        const int cb = bx * 16;
        const bool isB = wv >= 2;
        const int half = wv & 1;
        const int c0 = cb + half * 8;
        const int wc0 = (isB ? 16 : 0) + half * 8;
        float acc[8] = {0.f, 0.f, 0.f, 0.f, 0.f, 0.f, 0.f, 0.f};
        accum_lds<8>(xs, wt, lane, wc0, acc);
        float e[8];
#pragma unroll
        for (int c = 0; c < 8; ++c) {
            const float v = isB ? (acc[c] + bb1[c0 + c]) : acc[c];
            e[c] = __builtin_amdgcn_exp2f(v * EXPC);
        }
        __syncthreads();  // all waves done reading xs; safe to overwrite
        float* dstl = (isB ? vs : us) + lane * USTR + half * 8;
        *reinterpret_cast<float4*>(dstl) = make_float4(e[0], e[1], e[2], e[3]);
        *reinterpret_cast<float4*>(dstl + 4) =
            make_float4(e[4], e[5], e[6], e[7]);
        __syncthreads();

        const int lc = wv * 4;
        const float4 u = *reinterpret_cast<const float4*>(&us[lane * USTR + lc]);
        float s0 = 0.f, s1 = 0.f, s2 = 0.f, s3 = 0.f;
#pragma unroll 8
        for (int i = 0; i < 64; ++i) {
            const float4 v = *reinterpret_cast<const float4*>(&vs[i * USTR + lc]);
            s0 += __builtin_amdgcn_rcpf(fmaf(u.x, v.x, 1.0f));
            s1 += __builtin_amdgcn_rcpf(fmaf(u.y, v.y, 1.0f));
            s2 += __builtin_amdgcn_rcpf(fmaf(u.z, v.z, 1.0f));
            s3 += __builtin_amdgcn_rcpf(fmaf(u.w, v.w, 1.0f));
        }
        const float4 vj = *reinterpret_cast<const float4*>(&vs[lane * USTR + lc]);
        float4 o;
        o.x = (63.0f - 2.0f * (s0 - __builtin_amdgcn_rcpf(fmaf(u.x, vj.x, 1.0f)))) * 0.015625f;
        o.y = (63.0f - 2.0f * (s1 - __builtin_amdgcn_rcpf(fmaf(u.y, vj.y, 1.0f)))) * 0.015625f;
        o.z = (63.0f - 2.0f * (s2 - __builtin_amdgcn_rcpf(fmaf(u.z, vj.z, 1.0f)))) * 0.015625f;
        o.w = (63.0f - 2.0f * (s3 - __builtin_amdgcn_rcpf(fmaf(u.w, vj.w, 1.0f)))) * 0.015625f;
        *reinterpret_cast<float4*>(&S[(size_t)(r0 + lane) * 128 + cb + lc]) = o;
    } else {  // ---- unary T ----
        const int cg = (bx - 8) * 32 + wv * 8;
        float acc[8] = {0.f, 0.f, 0.f, 0.f, 0.f, 0.f, 0.f, 0.f};
        accum_lds<8>(xs, wt, lane, wv * 8, acc);
        float4 v0, v1;
        v0.x = tanh_fast(acc[0] + bu1[cg + 0]);
        v0.y = tanh_fast(acc[1] + bu1[cg + 1]);
        v0.z = tanh_fast(acc[2] + bu1[cg + 2]);
        v0.w = tanh_fast(acc[3] + bu1[cg + 3]);
        v1.x = tanh_fast(acc[4] + bu1[cg + 4]);
        v1.y = tanh_fast(acc[5] + bu1[cg + 5]);
        v1.z = tanh_fast(acc[6] + bu1[cg + 6]);
        v1.w = tanh_fast(acc[7] + bu1[cg + 7]);
        float* dst = T + (size_t)(r0 + lane) * 128 + cg;
        *reinterpret_cast<float4*>(dst) = v0;
        *reinterpret_cast<float4*>(dst + 4) = v1;
    }
}

// K4: out = T@Wu2.T + S'@Wb2.T + bu2 + (63/64)*bb2. grid (8,64):
// 16 cols/block, 4/wave. wt = [Wu2 16 rows | Wb2 16 rows] staged once;
// two sequential 128-k passes over one xs tile. LDS 50 KB -> 3 blocks/CU.
__global__ __launch_bounds__(256) void k4_out(
    const float* __restrict__ T, const float* __restrict__ S,
    const float* __restrict__ Wu2, const float* __restrict__ Wb2,
    const float* __restrict__ bu2, const float* __restrict__ bb2,
    float* __restrict__ out) {
    __shared__ float xs[64 * LS];
    __shared__ float wt[32 * 128];
    const int tid = threadIdx.x;
    const int lane = tid & 63;
    const int wv = __builtin_amdgcn_readfirstlane(tid >> 6);
    const int r0 = blockIdx.y * 64;
    const int cb = blockIdx.x * 16;
    const int cg = cb + wv * 4;
    stage64(T, r0, xs, tid);
    stage_w<16, 128>(Wu2, cb, wt, tid);
    stage_w<16, 128>(Wb2, cb, wt + 16 * 128, tid);
    __syncthreads();
    float acc[4] = {0.f, 0.f, 0.f, 0.f};
    accum_lds<4>(xs, wt, lane, wv * 4, acc);
    __syncthreads();  // done reading T tile
    stage64(S, r0, xs, tid);
    __syncthreads();
    accum_lds<4>(xs, wt, lane, 16 + wv * 4, acc);
    float4 o;
    o.x = acc[0] + bu2[cg + 0] + 0.984375f * bb2[cg + 0];
    o.y = acc[1] + bu2[cg + 1] + 0.984375f * bb2[cg + 1];
    o.z = acc[2] + bu2[cg + 2] + 0.984375f * bb2[cg + 2];
    o.w = acc[3] + bu2[cg + 3] + 0.984375f * bb2[cg + 3];
    *reinterpret_cast<float4*>(&out[(size_t)(r0 + lane) * 128 + cg]) = o;
}

extern "C" void kernel_launch(void* const* d_in, const int* in_sizes, int n_in,
                              void* d_out, int out_size, void* d_ws,
                              size_t ws_size, hipStream_t stream) {
    const float* t = (const float*)d_in[0];
    const float* x = (const float*)d_in[1];
    const float* W_lin = (const float*)d_in[2];
    const float* b_lin = (const float*)d_in[3];
    const float* Wu1 = (const float*)d_in[4];
    const float* bu1 = (const float*)d_in[5];
    const float* Wu2 = (const float*)d_in[6];
    const float* bu2 = (const float*)d_in[7];
    const float* Wb1 = (const float*)d_in[8];
    const float* bb1 = (const float*)d_in[9];
    const float* Wb2 = (const float*)d_in[10];
    const float* bb2 = (const float*)d_in[11];
    float* out = (float*)d_out;

    float* ws = (float*)d_ws;
    float* h = ws;                  // [4096,128]
    float* T = ws + 1 * ROW_ELEMS;  // [4096,128]
    float* S = ws + 2 * ROW_ELEMS;  // [4096,128] (pre-scaled by 1/64)

    // K1: h (512 blocks)
    k1_h<<<dim3(8, 64), 256, 0, stream>>>(x, W_lin, b_lin, t, h);
    // K2f: S' + T (768 blocks: 512 binary first, 256 unary)
    k2_fused<<<dim3(12, 64), 256, 0, stream>>>(h, Wu1, bu1, Wb1, bb1, T, S);
    // K4: out (512 blocks)
    k4_out<<<dim3(8, 64), 256, 0, stream>>>(T, S, Wu2, Wb2, bu2, bb2, out);
    (void)in_sizes; (void)n_in; (void)out_size; (void)ws_size;
}